// Round 21
// baseline (201.039 us; speedup 1.0000x reference)
//
#include <hip/hip_runtime.h>
#include <math.h>

// densemap = sum_k c_k * log2(relu(k^2 * conv_k(x)) + 1)
// conv_k = separable Gaussian (sigma = k/2), TF-SAME padding: pad_lo = (k-1)/2.
// Column/row window offsets union: -2..+3 (6 wide). k=1 kernel == identity.
//
// R14 (proven passing, 42.1us) with __launch_bounds__(256,6):
// reg cap 512/6 ~ 84 > R14's measured 56 VGPR (so no R18-style ring spill,
// which was the 64-reg tier at (256,8)), while raising the scheduler's
// waves/EU target from 4 -> 6 to lift the 30% occupancy cap.
// NOTE: the packed log tail (f32x2 y vectors + PKMUL/PKFMA res chain) failed
// correctness in R16/R17/R20 under three different staging schemes -- that
// construct is abandoned; tail stays scalar exactly as proven here.
//
// Tile 128x32 outputs per block (block 64x4, RPT=8); lane owns 2 adjacent
// columns via VOP3P packed fp32 (v_pk_add/mul/fma_f32; NO v_pk_max_f32 on
// gfx950). k^2 folded into log arg: log2(fma(k^2, max(t,0), 1)). Taps load as
// 6 f32x2 pairs (even: ds_read_b64, odd: ds_read2_b32). Inline-asm pk ops pin
// rings in VGPRs (LLVM never rematerializes asm results) -- this escaped the
// 24-VGPR remat pathology of rounds 2-13.

typedef float f32x2 __attribute__((ext_vector_type(2)));

struct Weights {
    float w6a, w6b, w6c, w5a, w5b, w5c, w4a, w4b, w3a, w3b, w2a; // 1D gaussian
    float c[6];     // regression slope coefficients
};

#define TXO 128
#define TYO 32
#define RPT 8           // rows per thread (block 64x4)
#define LDSW 136        // floats per staged row (16B-aligned stride)
#define SROWS 37        // staged rows: outputs -2..+34
#define NF4 (SROWS * 34)  // 1258 float4s per tile

#define GLOAD_LDS16(gp, lp) __builtin_amdgcn_global_load_lds( \
    (const __attribute__((address_space(1))) unsigned int*)(gp), \
    (__attribute__((address_space(3))) unsigned int*)(lp), 16, 0, 0)

#define PKADD(a, b) ({ f32x2 _d; \
    asm("v_pk_add_f32 %0, %1, %2" : "=v"(_d) : "v"(a), "v"(b)); _d; })
#define PKMUL(a, b) ({ f32x2 _d; \
    asm("v_pk_mul_f32 %0, %1, %2" : "=v"(_d) : "v"(a), "v"(b)); _d; })
#define PKFMA(a, b, c) ({ f32x2 _d; \
    asm("v_pk_fma_f32 %0, %1, %2, %3" : "=v"(_d) : "v"(a), "v"(b), "v"(c)); _d; })

__global__ __launch_bounds__(256, 6) void ldeb_kernel(const float* __restrict__ x,
                                                      float* __restrict__ out,
                                                      Weights W) {
    __shared__ float xs[SROWS * LDSW];
    const int img = blockIdx.z;
    const int bx = blockIdx.x, by = blockIdx.y;
    const int x0a = bx * TXO - 4;      // aligned staged-col base
    const int y0 = by * TYO - 2;       // staged-row base
    const float* __restrict__ xb = x + (size_t)img * 262144;
    const int tid = threadIdx.y * 64 + threadIdx.x;

    if (bx >= 1 && bx <= 2 && by >= 1 && by <= 14) {
        // interior: direct global->LDS, 16B/lane, dest linear in tid
#pragma unroll
        for (int it = 0; it < 5; ++it) {
            int i = tid + it * 256;
            if (i < NF4) {
                int row = i / 34;
                int c4 = i - row * 34;
                const float* gp = xb + (size_t)(y0 + row) * 512 + x0a + 4 * c4;
                GLOAD_LDS16(gp, &xs[i * 4]);
            }
        }
    } else {
        // border: reg-staged float4 with whole-float4 zero-fill
#pragma unroll
        for (int it = 0; it < 5; ++it) {
            int i = tid + it * 256;
            if (i < NF4) {
                int row = i / 34;
                int c4 = i - row * 34;
                int gy = y0 + row;
                int gc = x0a + 4 * c4;
                float4 v = make_float4(0.f, 0.f, 0.f, 0.f);
                if ((unsigned)gy < 512u && (unsigned)gc < 512u)
                    v = *(const float4*)(xb + (size_t)gy * 512 + gc);
                *(float4*)&xs[i * 4] = v;
            }
        }
    }
    __syncthreads();

    const int lane = threadIdx.x;        // 0..63; owns cols 2*lane, 2*lane+1
    const int Lr0 = threadIdx.y * RPT;   // this wave's staged-row base
    // tap -2 of col (bx*128 + 2*lane) is staged col 2*lane + 2
    const float* __restrict__ base = &xs[Lr0 * LDSW + 2 * lane + 2];
    float* __restrict__ ob = out + (size_t)img * 262144
                           + (size_t)(by * TYO + Lr0) * 512 + bx * TXO + 2 * lane;

    // broadcast weight pairs (one-time v_movs, hoisted)
    const f32x2 w6a = {W.w6a, W.w6a}, w6b = {W.w6b, W.w6b}, w6c = {W.w6c, W.w6c};
    const f32x2 w5a = {W.w5a, W.w5a}, w5b = {W.w5b, W.w5b}, w5c = {W.w5c, W.w5c};
    const f32x2 w4a = {W.w4a, W.w4a}, w4b = {W.w4b, W.w4b};
    const f32x2 w3a = {W.w3a, W.w3a}, w3b = {W.w3b, W.w3b};
    const f32x2 w2a = {W.w2a, W.w2a};

    f32x2 h6[6], h5[5], h4[4], h3[4], h2[3], h1[3];  // all indices ICEs

#define LOADP(dst, fptr) __builtin_memcpy(&(dst), (fptr), 8)

// load row j's 6 tap-pairs and form packed column-pair sums
#define ROWSUMS(j) \
        f32x2 E0, O0, E1, O1, E2, O2; \
        { const float* rp = base + (j) * LDSW; \
          LOADP(E0, rp);     LOADP(O0, rp + 1); \
          LOADP(E1, rp + 2); LOADP(O1, rp + 3); \
          LOADP(E2, rp + 4); LOADP(O2, rp + 5); } \
        f32x2 S05 = PKADD(E0, O2), S14 = PKADD(O0, E2), S23 = PKADD(E1, O1); \
        f32x2 S04 = PKADD(E0, E2), S13 = PKADD(O0, O1), V2 = E1;

// prologue row j = 0..4: fill rings only
#define PROW(j) { \
        ROWSUMS(j) \
        h6[(j) % 6] = PKFMA(w6c, S23, PKFMA(w6b, S14, PKMUL(w6a, S05))); \
        h5[(j) % 5] = PKFMA(w5c, V2,  PKFMA(w5b, S13, PKMUL(w5a, S04))); \
        h4[(j) % 4] = PKFMA(w4b, S23, PKMUL(w4a, S14)); \
        h3[(j) % 4] = PKFMA(w3b, V2,  PKMUL(w3a, S13)); \
        h2[(j) % 3] = PKMUL(w2a, S23); \
        h1[(j) % 3] = V2; \
    }

// y = log2(k2 * max(t,0) + 1), native v_log_f32
#define SLOG(t, k2) __builtin_amdgcn_logf(fmaf((k2), fmaxf((t), 0.0f), 1.0f))

// step r: read staged row r+5, emit output row r (both columns)
#define STEPR(r) { \
        ROWSUMS((r) + 5) \
        f32x2 H6 = PKFMA(w6c, S23, PKFMA(w6b, S14, PKMUL(w6a, S05))); \
        f32x2 t6 = PKMUL(w6a, PKADD(h6[(r) % 6], H6)); \
        t6 = PKFMA(w6b, PKADD(h6[((r) + 1) % 6], h6[((r) + 4) % 6]), t6); \
        t6 = PKFMA(w6c, PKADD(h6[((r) + 2) % 6], h6[((r) + 3) % 6]), t6); \
        f32x2 t5 = PKMUL(w5a, PKADD(h5[(r) % 5], h5[((r) + 4) % 5])); \
        t5 = PKFMA(w5b, PKADD(h5[((r) + 1) % 5], h5[((r) + 3) % 5]), t5); \
        t5 = PKFMA(w5c, h5[((r) + 2) % 5], t5); \
        f32x2 t4 = PKMUL(w4a, PKADD(h4[((r) + 1) % 4], h4[((r) + 4) % 4])); \
        t4 = PKFMA(w4b, PKADD(h4[((r) + 2) % 4], h4[((r) + 3) % 4]), t4); \
        f32x2 t3 = PKMUL(w3a, PKADD(h3[((r) + 1) % 4], h3[((r) + 3) % 4])); \
        t3 = PKFMA(w3b, h3[((r) + 2) % 4], t3); \
        f32x2 t2 = PKMUL(w2a, PKADD(h2[((r) + 2) % 3], h2[((r) + 3) % 3])); \
        f32x2 t1 = h1[((r) + 5) % 3]; /* row r+2, read before overwrite */ \
        h6[((r) + 5) % 6] = H6; \
        h5[((r) + 5) % 5] = PKFMA(w5c, V2,  PKFMA(w5b, S13, PKMUL(w5a, S04))); \
        h4[((r) + 5) % 4] = PKFMA(w4b, S23, PKMUL(w4a, S14)); \
        h3[((r) + 5) % 4] = PKFMA(w3b, V2,  PKMUL(w3a, S13)); \
        h2[((r) + 5) % 3] = PKMUL(w2a, S23); \
        h1[((r) + 5) % 3] = V2; \
        f32x2 res; \
        res.x = fmaf(W.c[5], SLOG(t6.x, 36.0f), \
                fmaf(W.c[4], SLOG(t5.x, 25.0f), \
                fmaf(W.c[3], SLOG(t4.x, 16.0f), \
                fmaf(W.c[2], SLOG(t3.x, 9.0f), \
                fmaf(W.c[1], SLOG(t2.x, 4.0f), \
                     W.c[0] * SLOG(t1.x, 1.0f)))))); \
        res.y = fmaf(W.c[5], SLOG(t6.y, 36.0f), \
                fmaf(W.c[4], SLOG(t5.y, 25.0f), \
                fmaf(W.c[3], SLOG(t4.y, 16.0f), \
                fmaf(W.c[2], SLOG(t3.y, 9.0f), \
                fmaf(W.c[1], SLOG(t2.y, 4.0f), \
                     W.c[0] * SLOG(t1.y, 1.0f)))))); \
        __builtin_memcpy(ob + (size_t)(r) * 512, &res, 8); \
    }

    PROW(0) PROW(1) PROW(2) PROW(3) PROW(4)
    STEPR(0) STEPR(1) STEPR(2) STEPR(3)
    STEPR(4) STEPR(5) STEPR(6) STEPR(7)

#undef STEPR
#undef PROW
#undef ROWSUMS
#undef LOADP
#undef SLOG
}

extern "C" void kernel_launch(void* const* d_in, const int* in_sizes, int n_in,
                              void* d_out, int out_size, void* d_ws, size_t ws_size,
                              hipStream_t stream) {
    const float* x = (const float*)d_in[0];
    float* out = (float*)d_out;

    Weights W;
    // regression coefficients: c_k = (X_k - mean(X)) / sum((X - mean)^2), X_k = log2(k)
    double X[6], mean = 0.0;
    for (int k = 1; k <= 6; ++k) { X[k - 1] = log2((double)k); mean += X[k - 1]; }
    mean /= 6.0;
    double denom = 0.0;
    for (int i = 0; i < 6; ++i) { double xc = X[i] - mean; denom += xc * xc; }
    for (int i = 0; i < 6; ++i) W.c[i] = (float)((X[i] - mean) / denom);

    // separable gaussian 1D weights, sigma = k/2 (k^2 folded into log args)
    float wv[6][6];
    for (int k = 1; k <= 6; ++k) {
        double sigma = k / 2.0;
        double g[6], s = 0.0;
        for (int i = 0; i < k; ++i) {
            double a = i - (k - 1) / 2.0;
            g[i] = exp(-(a * a) / (2.0 * sigma * sigma));
            s += g[i];
        }
        for (int i = 0; i < 6; ++i)
            wv[k - 1][i] = (i < k) ? (float)(g[i] / s) : 0.0f;
    }
    W.w6a = wv[5][0]; W.w6b = wv[5][1]; W.w6c = wv[5][2];
    W.w5a = wv[4][0]; W.w5b = wv[4][1]; W.w5c = wv[4][2];
    W.w4a = wv[3][0]; W.w4b = wv[3][1];
    W.w3a = wv[2][0]; W.w3b = wv[2][1];
    W.w2a = wv[1][0];

    dim3 grid(512 / TXO, 512 / TYO, 64);
    dim3 block(64, 4, 1);
    hipLaunchKernelGGL(ldeb_kernel, grid, block, 0, stream, x, out, W);
}

// Round 22
// 44.523 us; speedup vs baseline: 4.5154x; 4.5154x over previous
//
#include <hip/hip_runtime.h>
#include <math.h>

// densemap = sum_k c_k * log2(relu(k^2 * conv_k(x)) + 1)
// conv_k = separable Gaussian (sigma = k/2), TF-SAME padding: pad_lo = (k-1)/2.
// Column/row window offsets union: -2..+3 (6 wide). k=1 kernel == identity.
//
// R14 (proven 42.1us) with CONFLICT-FREE COLUMN PAIRING: lane owns columns
// (lane, lane+64) instead of (2*lane, 2*lane+1). Tap pair t loads as
// {rp[t], rp[t+64]} -> ds_read2_b32 offset0:t offset1:t+64, each component
// stride-1 across lanes (R14's adjacent pairing made stride-2 b32 components
// that hit only 16 odd/even banks = 4-way conflict, 2.5M cycles). Packed
// conv math is column-independent (broadcast weight pairs) so the compute
// core is IDENTICAL; only pair sourcing + the two scalar stores change.
// __launch_bounds__(256,4): anything higher spills the rings (R18: 309us,
// R21: 201us). Packed log tail abandoned (failed R16/R17/R20); tail scalar.

typedef float f32x2 __attribute__((ext_vector_type(2)));

struct Weights {
    float w6a, w6b, w6c, w5a, w5b, w5c, w4a, w4b, w3a, w3b, w2a; // 1D gaussian
    float c[6];     // regression slope coefficients
};

#define TXO 128
#define TYO 32
#define RPT 8           // rows per thread (block 64x4)
#define LDSW 136        // floats per staged row (16B-aligned stride)
#define SROWS 37        // staged rows: outputs -2..+34
#define NF4 (SROWS * 34)  // 1258 float4s per tile

#define GLOAD_LDS16(gp, lp) __builtin_amdgcn_global_load_lds( \
    (const __attribute__((address_space(1))) unsigned int*)(gp), \
    (__attribute__((address_space(3))) unsigned int*)(lp), 16, 0, 0)

#define PKADD(a, b) ({ f32x2 _d; \
    asm("v_pk_add_f32 %0, %1, %2" : "=v"(_d) : "v"(a), "v"(b)); _d; })
#define PKMUL(a, b) ({ f32x2 _d; \
    asm("v_pk_mul_f32 %0, %1, %2" : "=v"(_d) : "v"(a), "v"(b)); _d; })
#define PKFMA(a, b, c) ({ f32x2 _d; \
    asm("v_pk_fma_f32 %0, %1, %2, %3" : "=v"(_d) : "v"(a), "v"(b), "v"(c)); _d; })

__global__ __launch_bounds__(256, 4) void ldeb_kernel(const float* __restrict__ x,
                                                      float* __restrict__ out,
                                                      Weights W) {
    __shared__ float xs[SROWS * LDSW];
    const int img = blockIdx.z;
    const int bx = blockIdx.x, by = blockIdx.y;
    const int x0a = bx * TXO - 4;      // aligned staged-col base
    const int y0 = by * TYO - 2;       // staged-row base
    const float* __restrict__ xb = x + (size_t)img * 262144;
    const int tid = threadIdx.y * 64 + threadIdx.x;

    if (bx >= 1 && bx <= 2 && by >= 1 && by <= 14) {
        // interior: direct global->LDS, 16B/lane, dest linear in tid
#pragma unroll
        for (int it = 0; it < 5; ++it) {
            int i = tid + it * 256;
            if (i < NF4) {
                int row = i / 34;
                int c4 = i - row * 34;
                const float* gp = xb + (size_t)(y0 + row) * 512 + x0a + 4 * c4;
                GLOAD_LDS16(gp, &xs[i * 4]);
            }
        }
    } else {
        // border: reg-staged float4 with whole-float4 zero-fill
#pragma unroll
        for (int it = 0; it < 5; ++it) {
            int i = tid + it * 256;
            if (i < NF4) {
                int row = i / 34;
                int c4 = i - row * 34;
                int gy = y0 + row;
                int gc = x0a + 4 * c4;
                float4 v = make_float4(0.f, 0.f, 0.f, 0.f);
                if ((unsigned)gy < 512u && (unsigned)gc < 512u)
                    v = *(const float4*)(xb + (size_t)gy * 512 + gc);
                *(float4*)&xs[i * 4] = v;
            }
        }
    }
    __syncthreads();

    const int lane = threadIdx.x;        // 0..63; owns cols lane, lane+64
    const int Lr0 = threadIdx.y * RPT;   // this wave's staged-row base
    // tap -2 of col (bx*128 + lane) is staged col lane + 2
    const float* __restrict__ base = &xs[Lr0 * LDSW + lane + 2];
    float* __restrict__ ob = out + (size_t)img * 262144
                           + (size_t)(by * TYO + Lr0) * 512 + bx * TXO + lane;

    // broadcast weight pairs (one-time v_movs, hoisted)
    const f32x2 w6a = {W.w6a, W.w6a}, w6b = {W.w6b, W.w6b}, w6c = {W.w6c, W.w6c};
    const f32x2 w5a = {W.w5a, W.w5a}, w5b = {W.w5b, W.w5b}, w5c = {W.w5c, W.w5c};
    const f32x2 w4a = {W.w4a, W.w4a}, w4b = {W.w4b, W.w4b};
    const f32x2 w3a = {W.w3a, W.w3a}, w3b = {W.w3b, W.w3b};
    const f32x2 w2a = {W.w2a, W.w2a};

    f32x2 h6[6], h5[5], h4[4], h3[4], h2[3], h1[3];  // all indices ICEs

// load row j's 6 tap-pairs {col lane, col lane+64} and form packed sums;
// each component is a stride-1 b32 access (conflict-free); the two loads
// fuse into ds_read2_b32 offset0:t offset1:t+64.
#define ROWSUMS(j) \
        f32x2 T0, T1, T2, T3, T4, T5; \
        { const float* rp = base + (j) * LDSW; \
          T0.x = rp[0]; T0.y = rp[64]; \
          T1.x = rp[1]; T1.y = rp[65]; \
          T2.x = rp[2]; T2.y = rp[66]; \
          T3.x = rp[3]; T3.y = rp[67]; \
          T4.x = rp[4]; T4.y = rp[68]; \
          T5.x = rp[5]; T5.y = rp[69]; } \
        f32x2 S05 = PKADD(T0, T5), S14 = PKADD(T1, T4), S23 = PKADD(T2, T3); \
        f32x2 S04 = PKADD(T0, T4), S13 = PKADD(T1, T3), V2 = T2;

// prologue row j = 0..4: fill rings only
#define PROW(j) { \
        ROWSUMS(j) \
        h6[(j) % 6] = PKFMA(w6c, S23, PKFMA(w6b, S14, PKMUL(w6a, S05))); \
        h5[(j) % 5] = PKFMA(w5c, V2,  PKFMA(w5b, S13, PKMUL(w5a, S04))); \
        h4[(j) % 4] = PKFMA(w4b, S23, PKMUL(w4a, S14)); \
        h3[(j) % 4] = PKFMA(w3b, V2,  PKMUL(w3a, S13)); \
        h2[(j) % 3] = PKMUL(w2a, S23); \
        h1[(j) % 3] = V2; \
    }

// y = log2(k2 * max(t,0) + 1), native v_log_f32
#define SLOG(t, k2) __builtin_amdgcn_logf(fmaf((k2), fmaxf((t), 0.0f), 1.0f))

// step r: read staged row r+5, emit output row r (cols lane and lane+64)
#define STEPR(r) { \
        ROWSUMS((r) + 5) \
        f32x2 H6 = PKFMA(w6c, S23, PKFMA(w6b, S14, PKMUL(w6a, S05))); \
        f32x2 t6 = PKMUL(w6a, PKADD(h6[(r) % 6], H6)); \
        t6 = PKFMA(w6b, PKADD(h6[((r) + 1) % 6], h6[((r) + 4) % 6]), t6); \
        t6 = PKFMA(w6c, PKADD(h6[((r) + 2) % 6], h6[((r) + 3) % 6]), t6); \
        f32x2 t5 = PKMUL(w5a, PKADD(h5[(r) % 5], h5[((r) + 4) % 5])); \
        t5 = PKFMA(w5b, PKADD(h5[((r) + 1) % 5], h5[((r) + 3) % 5]), t5); \
        t5 = PKFMA(w5c, h5[((r) + 2) % 5], t5); \
        f32x2 t4 = PKMUL(w4a, PKADD(h4[((r) + 1) % 4], h4[((r) + 4) % 4])); \
        t4 = PKFMA(w4b, PKADD(h4[((r) + 2) % 4], h4[((r) + 3) % 4]), t4); \
        f32x2 t3 = PKMUL(w3a, PKADD(h3[((r) + 1) % 4], h3[((r) + 3) % 4])); \
        t3 = PKFMA(w3b, h3[((r) + 2) % 4], t3); \
        f32x2 t2 = PKMUL(w2a, PKADD(h2[((r) + 2) % 3], h2[((r) + 3) % 3])); \
        f32x2 t1 = h1[((r) + 5) % 3]; /* row r+2, read before overwrite */ \
        h6[((r) + 5) % 6] = H6; \
        h5[((r) + 5) % 5] = PKFMA(w5c, V2,  PKFMA(w5b, S13, PKMUL(w5a, S04))); \
        h4[((r) + 5) % 4] = PKFMA(w4b, S23, PKMUL(w4a, S14)); \
        h3[((r) + 5) % 4] = PKFMA(w3b, V2,  PKMUL(w3a, S13)); \
        h2[((r) + 5) % 3] = PKMUL(w2a, S23); \
        h1[((r) + 5) % 3] = V2; \
        float rx, ry; \
        rx = fmaf(W.c[5], SLOG(t6.x, 36.0f), \
             fmaf(W.c[4], SLOG(t5.x, 25.0f), \
             fmaf(W.c[3], SLOG(t4.x, 16.0f), \
             fmaf(W.c[2], SLOG(t3.x, 9.0f), \
             fmaf(W.c[1], SLOG(t2.x, 4.0f), \
                  W.c[0] * SLOG(t1.x, 1.0f)))))); \
        ry = fmaf(W.c[5], SLOG(t6.y, 36.0f), \
             fmaf(W.c[4], SLOG(t5.y, 25.0f), \
             fmaf(W.c[3], SLOG(t4.y, 16.0f), \
             fmaf(W.c[2], SLOG(t3.y, 9.0f), \
             fmaf(W.c[1], SLOG(t2.y, 4.0f), \
                  W.c[0] * SLOG(t1.y, 1.0f)))))); \
        ob[(size_t)(r) * 512] = rx; \
        ob[(size_t)(r) * 512 + 64] = ry; \
    }

    PROW(0) PROW(1) PROW(2) PROW(3) PROW(4)
    STEPR(0) STEPR(1) STEPR(2) STEPR(3)
    STEPR(4) STEPR(5) STEPR(6) STEPR(7)

#undef STEPR
#undef PROW
#undef ROWSUMS
#undef SLOG
}

extern "C" void kernel_launch(void* const* d_in, const int* in_sizes, int n_in,
                              void* d_out, int out_size, void* d_ws, size_t ws_size,
                              hipStream_t stream) {
    const float* x = (const float*)d_in[0];
    float* out = (float*)d_out;

    Weights W;
    // regression coefficients: c_k = (X_k - mean(X)) / sum((X - mean)^2), X_k = log2(k)
    double X[6], mean = 0.0;
    for (int k = 1; k <= 6; ++k) { X[k - 1] = log2((double)k); mean += X[k - 1]; }
    mean /= 6.0;
    double denom = 0.0;
    for (int i = 0; i < 6; ++i) { double xc = X[i] - mean; denom += xc * xc; }
    for (int i = 0; i < 6; ++i) W.c[i] = (float)((X[i] - mean) / denom);

    // separable gaussian 1D weights, sigma = k/2 (k^2 folded into log args)
    float wv[6][6];
    for (int k = 1; k <= 6; ++k) {
        double sigma = k / 2.0;
        double g[6], s = 0.0;
        for (int i = 0; i < k; ++i) {
            double a = i - (k - 1) / 2.0;
            g[i] = exp(-(a * a) / (2.0 * sigma * sigma));
            s += g[i];
        }
        for (int i = 0; i < 6; ++i)
            wv[k - 1][i] = (i < k) ? (float)(g[i] / s) : 0.0f;
    }
    W.w6a = wv[5][0]; W.w6b = wv[5][1]; W.w6c = wv[5][2];
    W.w5a = wv[4][0]; W.w5b = wv[4][1]; W.w5c = wv[4][2];
    W.w4a = wv[3][0]; W.w4b = wv[3][1];
    W.w3a = wv[2][0]; W.w3b = wv[2][1];
    W.w2a = wv[1][0];

    dim3 grid(512 / TXO, 512 / TYO, 64);
    dim3 block(64, 4, 1);
    hipLaunchKernelGGL(ldeb_kernel, grid, block, 0, stream, x, out, W);
}